// Round 4
// baseline (262.010 us; speedup 1.0000x reference)
//
#include <hip/hip_runtime.h>
#include <math.h>

typedef _Float16 half8 __attribute__((ext_vector_type(8)));
typedef float floatx4 __attribute__((ext_vector_type(4)));

#define SQ3 1.7320508075688772f

// bw layout: [path(4)][t(8)][s(2)][lane(64)][elem(8)] _Float16  (32768 = 64 KiB)
__global__ __launch_bounds__(256) void prep_w2(const float* __restrict__ W2,
                                               _Float16* __restrict__ bw) {
    int t = blockIdx.x * 256 + threadIdx.x;
    if (t >= 32768) return;
    int i    = t & 7;
    int l    = (t >> 3) & 63;
    int s    = (t >> 9) & 1;
    int tt   = (t >> 10) & 7;
    int path = t >> 13;
    int k   = s * 32 + (l >> 4) * 8 + i;
    int col = path * 128 + tt * 16 + (l & 15);
    float scale = 0.03125f * (path == 2 ? SQ3 : 1.0f);
    bw[t] = (_Float16)(W2[k * 512 + col] * scale);
}

__global__ __launch_bounds__(256) void count_kernel(const int* __restrict__ ei,
                                                    int* __restrict__ counts, int E) {
    int e = blockIdx.x * 256 + threadIdx.x;
    if (e < E) atomicAdd(&counts[ei[E + e]], 1);
}

// single block, 1024 threads: exclusive scan of counts -> offs, cursor; offs[nbins]=E
__global__ __launch_bounds__(1024) void scan_kernel(const int* __restrict__ counts,
                                                    int* __restrict__ offs,
                                                    int* __restrict__ cursor, int nbins) {
    __shared__ int part[1024];
    int tid = threadIdx.x;
    int per = (nbins + 1023) / 1024;
    int base = tid * per;
    int s = 0;
    for (int i = 0; i < per; ++i) {
        int idx = base + i;
        if (idx < nbins) s += counts[idx];
    }
    part[tid] = s;
    __syncthreads();
    for (int d = 1; d < 1024; d <<= 1) {
        int v = (tid >= d) ? part[tid - d] : 0;
        __syncthreads();
        part[tid] += v;
        __syncthreads();
    }
    int run = part[tid] - s;   // exclusive prefix
    for (int i = 0; i < per; ++i) {
        int idx = base + i;
        if (idx < nbins) {
            offs[idx] = run;
            cursor[idx] = run;
            run += counts[idx];
        }
    }
    if (tid == 1023) offs[nbins] = run;
}

__global__ __launch_bounds__(256) void scatter_kernel(const int* __restrict__ ei,
                                                      int* __restrict__ cursor,
                                                      int* __restrict__ perm, int E) {
    int e = blockIdx.x * 256 + threadIdx.x;
    if (e < E) {
        int slot = atomicAdd(&cursor[ei[E + e]], 1);
        perm[slot] = e;
    }
}

// mode 0: write 64-f16 message row to msg[e]   (CSR path)
// mode 1: atomicAdd f32 into out[dst]          (fallback path)
__global__ __launch_bounds__(256) void edge_kernel(
    const float* __restrict__ x, const float* __restrict__ pos,
    const int* __restrict__ ei, const float* __restrict__ W1,
    const _Float16* __restrict__ bw, _Float16* __restrict__ msg,
    float* __restrict__ out, int E, int mode)
{
    __shared__ __align__(16) float4 sW1v[16];
    __shared__ __align__(16) float4 s_geo[64];         // dx,dy,dz,len
    __shared__ int s_dst[64];
    __shared__ __align__(16) _Float16 s_xs[64][8];
    __shared__ __align__(16) _Float16 s_xv[64][24];
    __shared__ __align__(16) _Float16 s_hA[4][2][64][8];
    __shared__ __align__(16) _Float16 s_part[2][64][64];

    const int tid  = threadIdx.x;
    const int wave = tid >> 6;     // 0..3 == path A,B,C,D
    const int lane = tid & 63;
    const int ebase = blockIdx.x * 64;

    if (tid < 16) sW1v[tid] = reinterpret_cast<const float4*>(W1)[tid];

    half8 bfrag[8][2];
    {
        const half8* bsrc = (const half8*)bw;
        #pragma unroll
        for (int t = 0; t < 8; ++t)
            #pragma unroll
            for (int s = 0; s < 2; ++s)
                bfrag[t][s] = bsrc[(size_t)wave * 1024 + (t * 2 + s) * 64 + lane];
    }

    // ===== stage A: gather features + geometry + h =====
    {
        int eg_l = tid >> 2, q = tid & 3;
        int eg = ebase + eg_l;
        int ec = (eg < E) ? eg : (E - 1);
        int si = ei[ec];
        const float* xr = x + (size_t)si * 32 + q * 8;
        float4 va = *reinterpret_cast<const float4*>(xr);
        float4 vb = *reinterpret_cast<const float4*>(xr + 4);
        half8 hv;
        hv[0] = (_Float16)va.x; hv[1] = (_Float16)va.y;
        hv[2] = (_Float16)va.z; hv[3] = (_Float16)va.w;
        hv[4] = (_Float16)vb.x; hv[5] = (_Float16)vb.y;
        hv[6] = (_Float16)vb.z; hv[7] = (_Float16)vb.w;
        if (q == 0) *(half8*)&s_xs[eg_l][0] = hv;
        else        *(half8*)&s_xv[eg_l][(q - 1) * 8] = hv;
    }
    {
        int sub = tid >> 6;
        int l   = tid & 63;
        int el  = sub * 16 + (l & 15);
        int kg  = l >> 4;
        int eg  = ebase + el;
        int ec  = (eg < E) ? eg : (E - 1);
        int si = ei[ec];
        int di = ei[E + ec];
        float ex = pos[di * 3 + 0] - pos[si * 3 + 0];
        float ey = pos[di * 3 + 1] - pos[si * 3 + 1];
        float ez = pos[di * 3 + 2] - pos[si * 3 + 2];
        float len = sqrtf(ex * ex + ey * ey + ez * ez);
        len = fmaxf(len, 1e-8f);
        float inv = 1.0f / len;
        if (kg == 0) {
            s_geo[el] = make_float4(ex * inv, ey * inv, ez * inv, len);
            s_dst[el] = di;
        }
        #pragma unroll
        for (int s = 0; s < 2; ++s) {
            float4 w0 = sW1v[s * 8 + kg * 2 + 0];
            float4 w1 = sW1v[s * 8 + kg * 2 + 1];
            float ww[8] = {w0.x, w0.y, w0.z, w0.w, w1.x, w1.y, w1.z, w1.w};
            half8 ha;
            #pragma unroll
            for (int i = 0; i < 8; ++i) {
                float z = len * ww[i];
                ha[i] = (_Float16)(z / (1.0f + __expf(-z)));
            }
            *(half8*)&s_hA[sub][s][l][0] = ha;
        }
    }
    __syncthreads();

    // ===== stage B: 4 subtiles x 16 MFMA per wave + path epilogue =====
    const int wp  = lane & 15;
    const int er0 = (lane >> 4) * 4;
    #pragma unroll
    for (int sub = 0; sub < 4; ++sub) {
        half8 a0 = *(const half8*)&s_hA[sub][0][lane][0];
        half8 a1 = *(const half8*)&s_hA[sub][1][lane][0];
        floatx4 acc[8];
        #pragma unroll
        for (int t = 0; t < 8; ++t) {
            floatx4 z = {0.f, 0.f, 0.f, 0.f};
            z = __builtin_amdgcn_mfma_f32_16x16x32_f16(a0, bfrag[t][0], z, 0, 0, 0);
            acc[t] = __builtin_amdgcn_mfma_f32_16x16x32_f16(a1, bfrag[t][1], z, 0, 0, 0);
        }

        if (wave == 0) {                 // path A: ms = xs . wA
            #pragma unroll
            for (int r = 0; r < 4; ++r) {
                int e = sub * 16 + er0 + r;
                half8 xs = *(const half8*)&s_xs[e][0];
                float m = 0.f;
                #pragma unroll
                for (int u = 0; u < 8; ++u) m += (float)xs[u] * acc[u][r];
                s_part[0][e][wp] = (_Float16)m;
            }
        } else if (wave == 1) {          // path B: ms = (xv.dir) . wB
            #pragma unroll
            for (int r = 0; r < 4; ++r) {
                int e = sub * 16 + er0 + r;
                half8 v0 = *(const half8*)&s_xv[e][0];
                half8 v1 = *(const half8*)&s_xv[e][8];
                half8 v2 = *(const half8*)&s_xv[e][16];
                float4 g = s_geo[e];
                float xf[24];
                #pragma unroll
                for (int i = 0; i < 8; ++i) {
                    xf[i] = (float)v0[i]; xf[8 + i] = (float)v1[i];
                    xf[16 + i] = (float)v2[i];
                }
                float m = 0.f;
                #pragma unroll
                for (int u = 0; u < 8; ++u) {
                    float dot = xf[u*3+0]*g.x + xf[u*3+1]*g.y + xf[u*3+2]*g.z;
                    m += dot * acc[u][r];
                }
                s_part[1][e][wp] = (_Float16)m;
            }
        } else if (wave == 2) {          // path C: mv = (xs.wC) * sqrt3*dir
            #pragma unroll
            for (int r = 0; r < 4; ++r) {
                int e = sub * 16 + er0 + r;
                half8 xs = *(const half8*)&s_xs[e][0];
                float4 g = s_geo[e];
                float cw = 0.f;
                #pragma unroll
                for (int u = 0; u < 8; ++u) cw += (float)xs[u] * acc[u][r];
                s_part[0][e][16 + wp * 3 + 0] = (_Float16)(cw * g.x);
                s_part[0][e][16 + wp * 3 + 1] = (_Float16)(cw * g.y);
                s_part[0][e][16 + wp * 3 + 2] = (_Float16)(cw * g.z);
            }
        } else {                         // path D: mv = xv . wD
            #pragma unroll
            for (int r = 0; r < 4; ++r) {
                int e = sub * 16 + er0 + r;
                half8 v0 = *(const half8*)&s_xv[e][0];
                half8 v1 = *(const half8*)&s_xv[e][8];
                half8 v2 = *(const half8*)&s_xv[e][16];
                float xf[24];
                #pragma unroll
                for (int i = 0; i < 8; ++i) {
                    xf[i] = (float)v0[i]; xf[8 + i] = (float)v1[i];
                    xf[16 + i] = (float)v2[i];
                }
                float m0 = 0.f, m1 = 0.f, m2 = 0.f;
                #pragma unroll
                for (int u = 0; u < 8; ++u) {
                    float w = acc[u][r];
                    m0 += xf[u*3+0] * w;
                    m1 += xf[u*3+1] * w;
                    m2 += xf[u*3+2] * w;
                }
                s_part[1][e][16 + wp * 3 + 0] = (_Float16)m0;
                s_part[1][e][16 + wp * 3 + 1] = (_Float16)m1;
                s_part[1][e][16 + wp * 3 + 2] = (_Float16)m2;
            }
        }
    }
    __syncthreads();

    // ===== stage C: write message rows (CSR) or atomic scatter (fallback) =====
    {
        int c = tid & 63;
        int g = tid >> 6;
        if (mode == 0) {
            #pragma unroll
            for (int k = 0; k < 16; ++k) {
                int e  = g * 16 + k;
                int eg = ebase + e;
                if (eg < E) {
                    _Float16 v = s_part[0][e][c] + s_part[1][e][c];
                    msg[(size_t)eg * 64 + c] = v;
                }
            }
        } else {
            #pragma unroll
            for (int k = 0; k < 16; ++k) {
                int e  = g * 16 + k;
                int eg = ebase + e;
                if (eg < E) {
                    float v = (float)s_part[0][e][c] + (float)s_part[1][e][c];
                    atomicAdd(out + (size_t)s_dst[e] * 64 + c, v);
                }
            }
        }
    }
}

// one wave per node: sum CSR segment of msg rows, write out row
__global__ __launch_bounds__(256) void gather_kernel(
    const _Float16* __restrict__ msg, const int* __restrict__ offs,
    const int* __restrict__ perm, float* __restrict__ out, int N)
{
    int nwaves = gridDim.x * 4;
    int gw = blockIdx.x * 4 + (threadIdx.x >> 6);
    int lane = threadIdx.x & 63;
    for (int n = gw; n < N; n += nwaves) {
        int b  = offs[n];
        int e2 = offs[n + 1];
        float s = 0.f;
        for (int j = b; j < e2; ++j) {
            int row = perm[j];
            s += (float)msg[(size_t)row * 64 + lane];
        }
        out[(size_t)n * 64 + lane] = s;
    }
}

__global__ __launch_bounds__(256) void node_kernel(
    float* __restrict__ out, const float* __restrict__ Ws,
    const float* __restrict__ Wns, const float* __restrict__ Wg, int N)
{
    int n = blockIdx.x * 256 + threadIdx.x;
    if (n >= N) return;
    float* row = out + (size_t)n * 64;

    float os[16], ov[48];
    #pragma unroll
    for (int q = 0; q < 4; ++q) {
        float4 v = *reinterpret_cast<const float4*>(row + q * 4);
        os[q*4+0]=v.x; os[q*4+1]=v.y; os[q*4+2]=v.z; os[q*4+3]=v.w;
    }
    #pragma unroll
    for (int q = 0; q < 12; ++q) {
        float4 v = *reinterpret_cast<const float4*>(row + 16 + q * 4);
        ov[q*4+0]=v.x; ov[q*4+1]=v.y; ov[q*4+2]=v.z; ov[q*4+3]=v.w;
    }

    float sres[16], gres[16];
    #pragma unroll
    for (int w = 0; w < 16; ++w) {
        float a = 0.f, b = 0.f;
        #pragma unroll
        for (int u = 0; u < 16; ++u) {
            float o_u = os[u];
            a += o_u * Ws[u * 16 + w];
            b += o_u * Wg[u * 16 + w];
        }
        a *= 0.25f; b *= 0.25f;
        sres[w] = a / (1.0f + __expf(-a));
        gres[w] = 1.0f / (1.0f + __expf(-b));
    }

    float gated[48];
    #pragma unroll
    for (int w = 0; w < 16; ++w) {
        float n0 = 0.f, n1 = 0.f, n2 = 0.f;
        #pragma unroll
        for (int u = 0; u < 16; ++u) {
            float wn = Wns[u * 16 + w];
            n0 += ov[u*3+0] * wn;
            n1 += ov[u*3+1] * wn;
            n2 += ov[u*3+2] * wn;
        }
        float gw = gres[w] * 0.25f;
        gated[w*3+0] = n0 * gw;
        gated[w*3+1] = n1 * gw;
        gated[w*3+2] = n2 * gw;
    }

    #pragma unroll
    for (int q = 0; q < 4; ++q) {
        float4 v = make_float4(sres[q*4+0], sres[q*4+1], sres[q*4+2], sres[q*4+3]);
        *reinterpret_cast<float4*>(row + q * 4) = v;
    }
    #pragma unroll
    for (int q = 0; q < 12; ++q) {
        float4 v = make_float4(gated[q*4+0], gated[q*4+1], gated[q*4+2], gated[q*4+3]);
        *reinterpret_cast<float4*>(row + 16 + q * 4) = v;
    }
}

extern "C" void kernel_launch(void* const* d_in, const int* in_sizes, int n_in,
                              void* d_out, int out_size, void* d_ws, size_t ws_size,
                              hipStream_t stream) {
    const float* x   = (const float*)d_in[0];
    const float* pos = (const float*)d_in[1];
    const int*   ei  = (const int*)d_in[2];
    const float* W1  = (const float*)d_in[3];
    const float* W2  = (const float*)d_in[4];
    const float* Ws  = (const float*)d_in[5];
    const float* Wns = (const float*)d_in[6];
    const float* Wg  = (const float*)d_in[7];

    int N = in_sizes[0] / 32;
    int E = in_sizes[2] / 2;
    int ntiles = (E + 63) / 64;
    float* out = (float*)d_out;
    char* ws = (char*)d_ws;

    // workspace layout
    size_t off = 0;
    auto alloc = [&](size_t bytes) { size_t o = off; off = (off + bytes + 255) & ~255UL; return o; };
    size_t o_bw     = alloc(32768 * sizeof(_Float16));
    size_t o_counts = alloc((size_t)N * 4);
    size_t o_cursor = alloc((size_t)N * 4);
    size_t o_offs   = alloc((size_t)(N + 1) * 4);
    size_t o_perm   = alloc((size_t)E * 4);
    size_t o_msg    = alloc((size_t)E * 64 * sizeof(_Float16));
    size_t needed = off;

    _Float16* bw = (_Float16*)(ws + o_bw);
    prep_w2<<<128, 256, 0, stream>>>(W2, bw);

    if (ws_size >= needed) {
        int* counts = (int*)(ws + o_counts);
        int* cursor = (int*)(ws + o_cursor);
        int* offs   = (int*)(ws + o_offs);
        int* perm   = (int*)(ws + o_perm);
        _Float16* msg = (_Float16*)(ws + o_msg);

        hipMemsetAsync(counts, 0, (size_t)N * 4, stream);
        int eblk = (E + 255) / 256;
        count_kernel<<<eblk, 256, 0, stream>>>(ei, counts, E);
        scan_kernel<<<1, 1024, 0, stream>>>(counts, offs, cursor, N);
        scatter_kernel<<<eblk, 256, 0, stream>>>(ei, cursor, perm, E);
        edge_kernel<<<ntiles, 256, 0, stream>>>(x, pos, ei, W1, bw, msg, out, E, 0);
        gather_kernel<<<1024, 256, 0, stream>>>(msg, offs, perm, out, N);
        node_kernel<<<(N + 255) / 256, 256, 0, stream>>>(out, Ws, Wns, Wg, N);
    } else {
        // fallback: atomic scatter path
        hipMemsetAsync(out, 0, (size_t)N * 64 * sizeof(float), stream);
        edge_kernel<<<ntiles, 256, 0, stream>>>(x, pos, ei, W1, bw, nullptr, out, E, 1);
        node_kernel<<<(N + 255) / 256, 256, 0, stream>>>(out, Ws, Wns, Wg, N);
    }
}

// Round 5
// 106.973 us; speedup vs baseline: 2.4493x; 2.4493x over previous
//
#include <hip/hip_runtime.h>
#include <math.h>

typedef _Float16 half8 __attribute__((ext_vector_type(8)));
typedef float floatx4 __attribute__((ext_vector_type(4)));

#define SQ3 1.7320508075688772f

// bw layout: [path(4)][t(8)][s(2)][lane(64)][elem(8)] _Float16  (32768 = 64 KiB)
// bw value = W2[k][col] * scale, k = s*32 + (lane>>4)*8 + elem,
// col = path*128 + t*16 + (lane&15), scale = 1/32 (sqrt3 folded into path C)
__global__ __launch_bounds__(256) void prep_w2(const float* __restrict__ W2,
                                               _Float16* __restrict__ bw) {
    int t = blockIdx.x * 256 + threadIdx.x;
    if (t >= 32768) return;
    int i    = t & 7;
    int l    = (t >> 3) & 63;
    int s    = (t >> 9) & 1;
    int tt   = (t >> 10) & 7;
    int path = t >> 13;
    int k   = s * 32 + (l >> 4) * 8 + i;
    int col = path * 128 + tt * 16 + (l & 15);
    float scale = 0.03125f * (path == 2 ? SQ3 : 1.0f);
    bw[t] = (_Float16)(W2[k * 512 + col] * scale);
}

struct Pref {
    float4 xa, xb;
    float psx, psy, psz, pdx, pdy, pdz;
    int si, di;
};

__device__ __forceinline__ Pref issue_loads(int tile, int E,
        const int* __restrict__ ei, const float* __restrict__ x,
        const float* __restrict__ pos, int tid) {
    Pref p;
    int el = tid >> 2, q = tid & 3;
    int eg = tile * 64 + el;
    int ec = (eg < E) ? eg : (E - 1);
    p.si = ei[ec];
    p.di = ei[E + ec];
    const float* xr = x + (size_t)p.si * 32 + q * 8;
    p.xa = *reinterpret_cast<const float4*>(xr);
    p.xb = *reinterpret_cast<const float4*>(xr + 4);
    const float* ps = pos + (size_t)p.si * 3;
    const float* pd = pos + (size_t)p.di * 3;
    p.psx = ps[0]; p.psy = ps[1]; p.psz = ps[2];
    p.pdx = pd[0]; p.pdy = pd[1]; p.pdz = pd[2];
    return p;
}

__global__ __launch_bounds__(256) void edge_kernel(
    const float* __restrict__ x, const float* __restrict__ pos,
    const int* __restrict__ ei, const float* __restrict__ W1,
    const _Float16* __restrict__ bw, float* __restrict__ out,
    int E, int ntiles)
{
    __shared__ float sW1[64];
    __shared__ __align__(16) float4 s_geo[2][64];       // dx,dy,dz,len
    __shared__ int s_dst[2][64];
    __shared__ __align__(16) _Float16 s_xs[2][64][8];
    __shared__ __align__(16) _Float16 s_xv[2][64][24];
    __shared__ __align__(16) _Float16 s_hA[2][4][2][64][8];
    __shared__ __align__(16) _Float16 s_part[2][64][64];  // [A|B vs C|D pair][e][c]

    const int tid  = threadIdx.x;
    const int wave = tid >> 6;     // 0..3 == path A,B,C,D
    const int lane = tid & 63;

    if (tid < 64) sW1[tid] = W1[tid];

    // register-resident B fragments for this wave's path (16 frags = 64 VGPR)
    half8 bfrag[8][2];
    {
        const half8* bsrc = (const half8*)bw;
        #pragma unroll
        for (int t = 0; t < 8; ++t)
            #pragma unroll
            for (int s = 0; s < 2; ++s)
                bfrag[t][s] = bsrc[(size_t)wave * 1024 + (t * 2 + s) * 64 + lane];
    }

    int tile = blockIdx.x;
    if (tile >= ntiles) return;
    Pref p = issue_loads(tile, E, ei, x, pos, tid);
    __syncthreads();   // sW1 visible to all waves before first stage A

    int buf = 0;
    for (; tile < ntiles; tile += gridDim.x) {
        // ===== stage A: consume prefetched regs -> LDS (+geo, +h frags) =====
        {
            int el = tid >> 2, q = tid & 3;
            half8 hv;
            hv[0] = (_Float16)p.xa.x; hv[1] = (_Float16)p.xa.y;
            hv[2] = (_Float16)p.xa.z; hv[3] = (_Float16)p.xa.w;
            hv[4] = (_Float16)p.xb.x; hv[5] = (_Float16)p.xb.y;
            hv[6] = (_Float16)p.xb.z; hv[7] = (_Float16)p.xb.w;
            if (q == 0) *(half8*)&s_xs[buf][el][0] = hv;
            else        *(half8*)&s_xv[buf][el][(q - 1) * 8] = hv;

            float ex = p.pdx - p.psx;
            float ey = p.pdy - p.psy;
            float ez = p.pdz - p.psz;
            float len = fmaxf(sqrtf(ex * ex + ey * ey + ez * ez), 1e-8f);
            float inv = 1.0f / len;
            if (q == 0) {
                s_geo[buf][el] = make_float4(ex * inv, ey * inv, ez * inv, len);
                s_dst[buf][el] = p.di;
            }
            int sub = el >> 4;
            int l   = (q << 4) | (el & 15);
            #pragma unroll
            for (int s = 0; s < 2; ++s) {
                half8 ha;
                #pragma unroll
                for (int i = 0; i < 8; ++i) {
                    float z = len * sW1[s * 32 + q * 8 + i];
                    ha[i] = (_Float16)(z / (1.0f + __expf(-z)));
                }
                *(half8*)&s_hA[buf][sub][s][l][0] = ha;
            }
        }
        __syncthreads();   // bar1: tile's LDS ready

        // ---- prefetch next tile (loads fly during stage B) ----
        int nt = tile + gridDim.x;
        bool has = (nt < ntiles);
        Pref pn;
        if (has) pn = issue_loads(nt, E, ei, x, pos, tid);

        // ===== stage B: 4 subtiles x 16 MFMA per wave + path epilogue =====
        const int wp  = lane & 15;
        const int er0 = (lane >> 4) * 4;
        #pragma unroll
        for (int sub = 0; sub < 4; ++sub) {
            half8 a0 = *(const half8*)&s_hA[buf][sub][0][lane][0];
            half8 a1 = *(const half8*)&s_hA[buf][sub][1][lane][0];
            floatx4 acc[8];
            #pragma unroll
            for (int t = 0; t < 8; ++t) {
                floatx4 z = {0.f, 0.f, 0.f, 0.f};
                z = __builtin_amdgcn_mfma_f32_16x16x32_f16(a0, bfrag[t][0], z, 0, 0, 0);
                acc[t] = __builtin_amdgcn_mfma_f32_16x16x32_f16(a1, bfrag[t][1], z, 0, 0, 0);
            }

            if (wave == 0) {                 // path A: ms = xs . wA
                #pragma unroll
                for (int r = 0; r < 4; ++r) {
                    int e = sub * 16 + er0 + r;
                    half8 xs = *(const half8*)&s_xs[buf][e][0];
                    float m = 0.f;
                    #pragma unroll
                    for (int u = 0; u < 8; ++u) m += (float)xs[u] * acc[u][r];
                    s_part[0][e][wp] = (_Float16)m;
                }
            } else if (wave == 1) {          // path B: ms = (xv.dir) . wB
                #pragma unroll
                for (int r = 0; r < 4; ++r) {
                    int e = sub * 16 + er0 + r;
                    half8 v0 = *(const half8*)&s_xv[buf][e][0];
                    half8 v1 = *(const half8*)&s_xv[buf][e][8];
                    half8 v2 = *(const half8*)&s_xv[buf][e][16];
                    float4 g = s_geo[buf][e];
                    float xf[24];
                    #pragma unroll
                    for (int i = 0; i < 8; ++i) {
                        xf[i] = (float)v0[i]; xf[8 + i] = (float)v1[i];
                        xf[16 + i] = (float)v2[i];
                    }
                    float m = 0.f;
                    #pragma unroll
                    for (int u = 0; u < 8; ++u) {
                        float dot = xf[u*3+0]*g.x + xf[u*3+1]*g.y + xf[u*3+2]*g.z;
                        m += dot * acc[u][r];
                    }
                    s_part[1][e][wp] = (_Float16)m;
                }
            } else if (wave == 2) {          // path C: mv = (xs.wC) * sqrt3*dir
                #pragma unroll
                for (int r = 0; r < 4; ++r) {
                    int e = sub * 16 + er0 + r;
                    half8 xs = *(const half8*)&s_xs[buf][e][0];
                    float4 g = s_geo[buf][e];
                    float cw = 0.f;
                    #pragma unroll
                    for (int u = 0; u < 8; ++u) cw += (float)xs[u] * acc[u][r];
                    s_part[0][e][16 + wp * 3 + 0] = (_Float16)(cw * g.x);
                    s_part[0][e][16 + wp * 3 + 1] = (_Float16)(cw * g.y);
                    s_part[0][e][16 + wp * 3 + 2] = (_Float16)(cw * g.z);
                }
            } else {                         // path D: mv = xv . wD
                #pragma unroll
                for (int r = 0; r < 4; ++r) {
                    int e = sub * 16 + er0 + r;
                    half8 v0 = *(const half8*)&s_xv[buf][e][0];
                    half8 v1 = *(const half8*)&s_xv[buf][e][8];
                    half8 v2 = *(const half8*)&s_xv[buf][e][16];
                    float xf[24];
                    #pragma unroll
                    for (int i = 0; i < 8; ++i) {
                        xf[i] = (float)v0[i]; xf[8 + i] = (float)v1[i];
                        xf[16 + i] = (float)v2[i];
                    }
                    float m0 = 0.f, m1 = 0.f, m2 = 0.f;
                    #pragma unroll
                    for (int u = 0; u < 8; ++u) {
                        float w = acc[u][r];
                        m0 += xf[u*3+0] * w;
                        m1 += xf[u*3+1] * w;
                        m2 += xf[u*3+2] * w;
                    }
                    s_part[1][e][16 + wp * 3 + 0] = (_Float16)m0;
                    s_part[1][e][16 + wp * 3 + 1] = (_Float16)m1;
                    s_part[1][e][16 + wp * 3 + 2] = (_Float16)m2;
                }
            }
        }
        __syncthreads();   // bar2: partials ready

        // ===== stage C: coalesced atomic scatter, 64 edges =====
        {
            int c = tid & 63;
            int g = tid >> 6;
            #pragma unroll
            for (int k = 0; k < 16; ++k) {
                int e  = g * 16 + k;
                int eg = tile * 64 + e;
                if (eg < E) {
                    float v = (float)s_part[0][e][c] + (float)s_part[1][e][c];
                    atomicAdd(out + (size_t)s_dst[buf][e] * 64 + c, v);
                }
            }
        }
        p = pn;
        buf ^= 1;
    }
}

__global__ __launch_bounds__(256) void node_kernel(
    float* __restrict__ out, const float* __restrict__ Ws,
    const float* __restrict__ Wns, const float* __restrict__ Wg, int N)
{
    int n = blockIdx.x * 256 + threadIdx.x;
    if (n >= N) return;
    float* row = out + (size_t)n * 64;

    float os[16], ov[48];
    #pragma unroll
    for (int q = 0; q < 4; ++q) {
        float4 v = *reinterpret_cast<const float4*>(row + q * 4);
        os[q*4+0]=v.x; os[q*4+1]=v.y; os[q*4+2]=v.z; os[q*4+3]=v.w;
    }
    #pragma unroll
    for (int q = 0; q < 12; ++q) {
        float4 v = *reinterpret_cast<const float4*>(row + 16 + q * 4);
        ov[q*4+0]=v.x; ov[q*4+1]=v.y; ov[q*4+2]=v.z; ov[q*4+3]=v.w;
    }

    float sres[16], gres[16];
    #pragma unroll
    for (int w = 0; w < 16; ++w) {
        float a = 0.f, b = 0.f;
        #pragma unroll
        for (int u = 0; u < 16; ++u) {
            float o_u = os[u];
            a += o_u * Ws[u * 16 + w];
            b += o_u * Wg[u * 16 + w];
        }
        a *= 0.25f; b *= 0.25f;
        sres[w] = a / (1.0f + __expf(-a));
        gres[w] = 1.0f / (1.0f + __expf(-b));
    }

    float gated[48];
    #pragma unroll
    for (int w = 0; w < 16; ++w) {
        float n0 = 0.f, n1 = 0.f, n2 = 0.f;
        #pragma unroll
        for (int u = 0; u < 16; ++u) {
            float wn = Wns[u * 16 + w];
            n0 += ov[u*3+0] * wn;
            n1 += ov[u*3+1] * wn;
            n2 += ov[u*3+2] * wn;
        }
        float gw = gres[w] * 0.25f;
        gated[w*3+0] = n0 * gw;
        gated[w*3+1] = n1 * gw;
        gated[w*3+2] = n2 * gw;
    }

    #pragma unroll
    for (int q = 0; q < 4; ++q) {
        float4 v = make_float4(sres[q*4+0], sres[q*4+1], sres[q*4+2], sres[q*4+3]);
        *reinterpret_cast<float4*>(row + q * 4) = v;
    }
    #pragma unroll
    for (int q = 0; q < 12; ++q) {
        float4 v = make_float4(gated[q*4+0], gated[q*4+1], gated[q*4+2], gated[q*4+3]);
        *reinterpret_cast<float4*>(row + 16 + q * 4) = v;
    }
}

extern "C" void kernel_launch(void* const* d_in, const int* in_sizes, int n_in,
                              void* d_out, int out_size, void* d_ws, size_t ws_size,
                              hipStream_t stream) {
    const float* x   = (const float*)d_in[0];
    const float* pos = (const float*)d_in[1];
    const int*   ei  = (const int*)d_in[2];
    const float* W1  = (const float*)d_in[3];
    const float* W2  = (const float*)d_in[4];
    const float* Ws  = (const float*)d_in[5];
    const float* Wns = (const float*)d_in[6];
    const float* Wg  = (const float*)d_in[7];

    int N = in_sizes[0] / 32;
    int E = in_sizes[2] / 2;
    int ntiles = (E + 63) / 64;
    float* out = (float*)d_out;
    _Float16* bw = (_Float16*)d_ws;

    hipMemsetAsync(out, 0, (size_t)N * 64 * sizeof(float), stream);
    prep_w2<<<128, 256, 0, stream>>>(W2, bw);
    int nblk = ntiles < 960 ? ntiles : 960;
    edge_kernel<<<nblk, 256, 0, stream>>>(x, pos, ei, W1, bw, out, E, ntiles);
    node_kernel<<<(N + 255) / 256, 256, 0, stream>>>(out, Ws, Wns, Wg, N);
}